// Round 6
// baseline (683.475 us; speedup 1.0000x reference)
//
#include <hip/hip_runtime.h>

// DecoderGRU: h_{t+1} = GRUCell(h_t, h_t), 64 steps. Combined gates: r,z use
// (W_ih+W_hh); n keeps i_n,h_n -> one [512,1024]x[1024,4096] bf16 GEMM + fused
// GRU update per step. 64 step launches (grid-wide dep between steps).
// R6: B weights live in registers (loaded once/step from L2-hot WB); only A
// flows through LDS (triple-buffered, counted vmcnt(2)); setprio around MFMA;
// split-G epilogue (one barrier).

typedef float  f32x4 __attribute__((ext_vector_type(4)));
typedef __bf16 bf16x8 __attribute__((ext_vector_type(8)));
typedef unsigned short u16x8 __attribute__((ext_vector_type(8)));
typedef unsigned short u16x4 __attribute__((ext_vector_type(4)));

#define GPTR(p) ((const __attribute__((address_space(1))) unsigned int*)(p))
#define LPTR(p) ((__attribute__((address_space(3))) unsigned int*)(p))

// ws layout
#define WB_OFF   0u            // 8 MB frag-packed bf16 weights
#define BIAS_OFF 8388608u      // 16 KB combined biases [4][1024]
#define HWS_OFF  8404992u      // 2 MB fp32 h
#define A0_OFF   10502144u     // 1 MB frag-packed bf16 h (ping)
#define A1_OFF   11550720u     // 1 MB (pong)

__device__ __forceinline__ unsigned short f2bf(float f){
  unsigned int u = __builtin_bit_cast(unsigned int, f);
  u = (u + 0x7FFFu + ((u >> 16) & 1u)) >> 16;
  return (unsigned short)u;
}

// ---------------------------------------------------------------------------
// B layout: byte = j*262144 + c*32768 + fb*1024 + lane*16 + (k&7)*2
//   j=col>>5, c=k>>7, fb=(((k>>5)&3)*4+g)*2+((col>>4)&1),
//   lane=(col&15)+((k>>3)&3)*16.   gates: 0=r(+) 1=z(+) 2=i_n(ih) 3=h_n(hh)
// ---------------------------------------------------------------------------
extern "C" __global__ void gru_weights(const float* __restrict__ wih,
                                       const float* __restrict__ whh,
                                       char* __restrict__ WB){
  int gt  = blockIdx.x * 256 + threadIdx.x;   // 524288 threads
  int k0  = (gt & 127) << 3;                  // 8 k's per thread
  int gid = gt >> 7;
  int g   = gid >> 10, colg = gid & 1023;
  int srow = (g < 2) ? g * 1024 + colg : 2048 + colg;
  const float* pa = ((g == 3) ? whh : wih) + srow * 1024 + k0;
  f32x4 v0 = ((const f32x4*)pa)[0];
  f32x4 v1 = ((const f32x4*)pa)[1];
  if (g < 2){
    const float* pb = whh + srow * 1024 + k0;
    v0 += ((const f32x4*)pb)[0];
    v1 += ((const f32x4*)pb)[1];
  }
  u16x8 o;
  #pragma unroll
  for (int e = 0; e < 4; e++){ o[e] = f2bf(v0[e]); o[4 + e] = f2bf(v1[e]); }
  int cck = k0 >> 7;
  int fb  = (((k0 >> 5) & 3) * 4 + g) * 2 + ((colg >> 4) & 1);
  int lane= (colg & 15) + ((k0 >> 3) & 3) * 16;
  int addr= (colg >> 5) * 262144 + cck * 32768 + fb * 1024 + lane * 16;
  *(u16x8*)(WB + addr) = o;
}

// ---------------------------------------------------------------------------
// A layout: byte = (row>>6)*131072 + (hk>>7)*16384
//           + (((hk>>5)&3)*4 + ((row&63)>>4))*1024
//           + ((row&15)+((hk>>3)&3)*16)*16 + (hk&7)*2
// ---------------------------------------------------------------------------
extern "C" __global__ void gru_init(const float* __restrict__ hidden,
                                    const float* __restrict__ bih,
                                    const float* __restrict__ bhh,
                                    float* __restrict__ hws,
                                    char* __restrict__ A0,
                                    float* __restrict__ bias){
  int gt = blockIdx.x * 256 + threadIdx.x;    // 65536 threads, 8 elems each
  int e0 = gt * 8;
  int r  = e0 >> 10, c0 = e0 & 1023;
  f32x4 v0 = ((const f32x4*)(hidden + e0))[0];
  f32x4 v1 = ((const f32x4*)(hidden + e0))[1];
  ((f32x4*)(hws + e0))[0] = v0;
  ((f32x4*)(hws + e0))[1] = v1;
  u16x8 o;
  #pragma unroll
  for (int e = 0; e < 4; e++){ o[e] = f2bf(v0[e]); o[4 + e] = f2bf(v1[e]); }
  int addr = (r >> 6) * 131072 + (c0 >> 7) * 16384
           + (((c0 >> 5) & 3) * 4 + ((r & 63) >> 4)) * 1024
           + ((r & 15) + ((c0 >> 3) & 3) * 16) * 16;
  *(u16x8*)(A0 + addr) = o;
  if (blockIdx.x < 16){
    int bi = blockIdx.x * 256 + threadIdx.x;  // 4096 bias entries
    int g = bi >> 10, c = bi & 1023;
    float v = (g == 0) ? bih[c]        + bhh[c]
            : (g == 1) ? bih[1024 + c] + bhh[1024 + c]
            : (g == 2) ? bih[2048 + c] : bhh[2048 + c];
    bias[bi] = v;
  }
}

// ---------------------------------------------------------------------------
// Step kernel. grid 256 (1 block/CU), 512 thr = 8 waves = (gate g, K-half kh).
// B in regs: b[16][2] bf16x8 (128 VGPR, AGPR-eligible). A triple-buffered in
// LDS @ 0/16384/32768; G split-regions [8][64][34] f32 @ 49152.
// K-loop: {STAGE(c+2); setprio(1); 16 MFMA; setprio(0); vmcnt(2); barrier}.
// ---------------------------------------------------------------------------
extern "C" __global__ void __launch_bounds__(512, 2)
gru_step(const char* __restrict__ Acur, char* __restrict__ Anext,
         float* __restrict__ hws, const char* __restrict__ WB,
         const float* __restrict__ bias, float* __restrict__ out, int t)
{
  __shared__ __align__(16) char lds[118784];
  const int tid = threadIdx.x;
  const int wv = tid >> 6, ln = tid & 63;
  const int g = wv & 3, kh = wv >> 2;
  const int lrow = ln & 15, lq = ln >> 4;
  const int bid = blockIdx.x;
  const int j  = (bid & 7) * 4 + ((bid >> 3) & 3);
  const int rb = bid >> 5;
  const int abase = rb * 131072;
  const int bbase = j * 262144;

  // ---- B into registers (once per step; WB is L2-hot) ----
  bf16x8 b[16][2];
  #pragma unroll
  for (int c = 0; c < 8; c++)
    #pragma unroll
    for (int p = 0; p < 2; p++)
      #pragma unroll
      for (int n = 0; n < 2; n++)
        b[c * 2 + p][n] = *(const bf16x8*)(WB + bbase + c * 32768
                            + (((kh * 2 + p) * 4 + g) * 2 + n) * 1024 + ln * 16);

  f32x4 acc[4][2];
  #pragma unroll
  for (int m = 0; m < 4; m++)
    #pragma unroll
    for (int n = 0; n < 2; n++) acc[m][n] = f32x4{0.f,0.f,0.f,0.f};

#define STAGE(cc, buf) do { \
    _Pragma("unroll") \
    for (int i = 0; i < 2; i++) \
      __builtin_amdgcn_global_load_lds( \
          GPTR(Acur + abase + (cc) * 16384 + tid * 16 + i * 8192), \
          LPTR(lds + (buf) * 16384 + tid * 16 + i * 8192), 16, 0, 0); \
  } while (0)

  STAGE(0, 0);
  STAGE(1, 1);
  asm volatile("s_waitcnt vmcnt(2)" ::: "memory");
  __builtin_amdgcn_s_barrier();

  #pragma unroll
  for (int c = 0; c < 8; c++){
    if (c < 6) STAGE(c + 2, (c + 2) % 3);
    __builtin_amdgcn_s_setprio(1);
    #pragma unroll
    for (int p = 0; p < 2; p++){
      const int ks = kh * 2 + p;
      bf16x8 a[4];
      #pragma unroll
      for (int m = 0; m < 4; m++)
        a[m] = *(const bf16x8*)(lds + (c % 3) * 16384 + (ks * 4 + m) * 1024 + ln * 16);
      #pragma unroll
      for (int m = 0; m < 4; m++)
        #pragma unroll
        for (int n = 0; n < 2; n++)
          acc[m][n] = __builtin_amdgcn_mfma_f32_16x16x32_bf16(a[m], b[c * 2 + p][n], acc[m][n], 0, 0, 0);
    }
    __builtin_amdgcn_s_setprio(0);
    if (c < 6){
      asm volatile("s_waitcnt vmcnt(2)" ::: "memory");
      __builtin_amdgcn_s_barrier();
    } else if (c == 6){
      asm volatile("s_waitcnt vmcnt(0)" ::: "memory");
      __builtin_amdgcn_s_barrier();
    }
  }
#undef STAGE

  // ---- epilogue: split G regions, ONE barrier ----
  // G[q][row 64][34], q = kh*4+g; reader sums q and q+4, adds bias.
  float* G = (float*)(lds + 49152);
  const int q = kh * 4 + g;
  #pragma unroll
  for (int m = 0; m < 4; m++)
    #pragma unroll
    for (int r4 = 0; r4 < 4; r4++){
      int row = m * 16 + lq * 4 + r4;
      G[q * 2176 + row * 34 + lrow]      = acc[m][0][r4];
      G[q * 2176 + row * 34 + 16 + lrow] = acc[m][1][r4];
    }
  __syncthreads();

  const int erow = tid >> 3, ec0 = (tid & 7) * 4;
  const int base34 = erow * 34 + ec0;
  const int grow = rb * 64 + erow;
  const int gcol = j * 32 + ec0;
  f32x4 vr = *(const f32x4*)(G + 0 * 2176 + base34) + *(const f32x4*)(G + 4 * 2176 + base34);
  f32x4 vz = *(const f32x4*)(G + 1 * 2176 + base34) + *(const f32x4*)(G + 5 * 2176 + base34);
  f32x4 vi = *(const f32x4*)(G + 2 * 2176 + base34) + *(const f32x4*)(G + 6 * 2176 + base34);
  f32x4 vh = *(const f32x4*)(G + 3 * 2176 + base34) + *(const f32x4*)(G + 7 * 2176 + base34);
  vr += *(const f32x4*)(bias + gcol);
  vz += *(const f32x4*)(bias + 1024 + gcol);
  vi += *(const f32x4*)(bias + 2048 + gcol);
  vh += *(const f32x4*)(bias + 3072 + gcol);
  f32x4 hold = *(const f32x4*)(hws + grow * 1024 + gcol);
  f32x4 vout; u16x4 hb;
  #pragma unroll
  for (int e = 0; e < 4; e++){
    float rr = 1.f / (1.f + __expf(-vr[e]));
    float zz = 1.f / (1.f + __expf(-vz[e]));
    float x  = vi[e] + rr * vh[e];
    float ex = __expf(-2.f * x);
    float nn = (1.f - ex) / (1.f + ex);
    float hn = nn + zz * (hold[e] - nn);
    vout[e] = hn;
    hb[e] = f2bf(hn);
  }
  *(f32x4*)(out + (size_t)grow * 65536 + (size_t)t * 1024 + gcol) = vout;
  *(f32x4*)(hws + grow * 1024 + gcol) = vout;
  int aaddr = rb * 131072 + (j >> 2) * 16384
            + ((j & 3) * 4 + (erow >> 4)) * 1024
            + ((erow & 15) + ((ec0 >> 3) & 3) * 16) * 16 + (ec0 & 7) * 2;
  *(u16x4*)(Anext + aaddr) = hb;
}

// ---------------------------------------------------------------------------
extern "C" void kernel_launch(void* const* d_in, const int* in_sizes, int n_in,
                              void* d_out, int out_size, void* d_ws, size_t ws_size,
                              hipStream_t stream){
  const float* hidden = (const float*)d_in[0];
  const float* wih    = (const float*)d_in[1];
  const float* whh    = (const float*)d_in[2];
  const float* bih    = (const float*)d_in[3];
  const float* bhh    = (const float*)d_in[4];
  char*  ws   = (char*)d_ws;
  char*  WB   = ws + WB_OFF;
  float* bias = (float*)(ws + BIAS_OFF);
  float* hws  = (float*)(ws + HWS_OFF);
  char*  A0   = ws + A0_OFF;
  char*  A1   = ws + A1_OFF;
  float* out  = (float*)d_out;

  hipLaunchKernelGGL(gru_weights, dim3(2048), dim3(256), 0, stream, wih, whh, WB);
  hipLaunchKernelGGL(gru_init,    dim3(256),  dim3(256), 0, stream,
                     hidden, bih, bhh, hws, A0, bias);
  for (int t = 0; t < 64; t++){
    char* Asrc = (t & 1) ? A1 : A0;
    char* Adst = (t & 1) ? A0 : A1;
    hipLaunchKernelGGL(gru_step, dim3(256), dim3(512), 0, stream,
                       (const char*)Asrc, Adst, hws,
                       (const char*)WB, (const float*)bias, out, t);
  }
}